// Round 1
// baseline (604.259 us; speedup 1.0000x reference)
//
#include <hip/hip_runtime.h>
#include <hip/hip_bf16.h>
#include <math.h>

#define NF_IN 512
#define NF_OUT 256
#define HEADS 6
#define NCOLS (HEADS * NF_OUT)   // 1536
#define SLOPE 0.2f

__device__ __forceinline__ float bf2f(unsigned short u) {
  unsigned int x = ((unsigned int)u) << 16;
  return __uint_as_float(x);
}
__device__ __forceinline__ unsigned short f2bf(float f) {
  unsigned int x = __float_as_uint(f);
  unsigned int lsb = (x >> 16) & 1u;
  x += 0x7fffu + lsb;
  return (unsigned short)(x >> 16);
}

// ---------------- zero init ----------------
__global__ void zero_kernel(int* __restrict__ p, int n) {
  int i = blockIdx.x * blockDim.x + threadIdx.x;
  if (i < n) p[i] = 0;
}

// ---------------- fp32 GEMM: xp_feat(bf16) = data[M,512] @ W_feat[512,1536] ----------------
#define BM 128
#define BN 128
#define BK 16
__global__ __launch_bounds__(256) void gemm_feat_kernel(
    const float* __restrict__ A, const float* __restrict__ B,
    unsigned short* __restrict__ C, int M) {
  __shared__ float As[BK][BM + 4];
  __shared__ float Bs[BK][BN + 4];
  const int tid = threadIdx.x;
  const int tx = tid & 15, ty = tid >> 4;
  const int row0 = blockIdx.y * BM;
  const int col0 = blockIdx.x * BN;

  const int arow = tid >> 2;        // 0..63
  const int acol4 = tid & 3;        // float4 idx within 16 cols
  const int brow = tid >> 5;        // 0..7
  const int bcol4 = tid & 31;       // float4 idx within 128 cols

  float acc[8][8];
#pragma unroll
  for (int i = 0; i < 8; ++i)
#pragma unroll
    for (int j = 0; j < 8; ++j) acc[i][j] = 0.f;

  for (int k0 = 0; k0 < NF_IN; k0 += BK) {
#pragma unroll
    for (int rr = 0; rr < 2; ++rr) {
      int r = arow + rr * 64;
      int grow = row0 + r;
      float4 v = make_float4(0.f, 0.f, 0.f, 0.f);
      if (grow < M) v = *(const float4*)(A + (size_t)grow * NF_IN + k0 + acol4 * 4);
      As[acol4 * 4 + 0][r] = v.x;
      As[acol4 * 4 + 1][r] = v.y;
      As[acol4 * 4 + 2][r] = v.z;
      As[acol4 * 4 + 3][r] = v.w;
    }
#pragma unroll
    for (int rr = 0; rr < 2; ++rr) {
      int r = brow + rr * 8;
      float4 v = *(const float4*)(B + (size_t)(k0 + r) * NCOLS + col0 + bcol4 * 4);
      *(float4*)(&Bs[r][bcol4 * 4]) = v;
    }
    __syncthreads();
#pragma unroll
    for (int kk = 0; kk < BK; ++kk) {
      float a[8], b[8];
      *(float4*)(a) = *(const float4*)(&As[kk][ty * 4]);
      *(float4*)(a + 4) = *(const float4*)(&As[kk][64 + ty * 4]);
      *(float4*)(b) = *(const float4*)(&Bs[kk][tx * 4]);
      *(float4*)(b + 4) = *(const float4*)(&Bs[kk][64 + tx * 4]);
#pragma unroll
      for (int i = 0; i < 8; ++i)
#pragma unroll
        for (int j = 0; j < 8; ++j) acc[i][j] += a[i] * b[j];
    }
    __syncthreads();
  }
#pragma unroll
  for (int ih = 0; ih < 2; ++ih)
#pragma unroll
    for (int i = 0; i < 4; ++i) {
      int r = row0 + ih * 64 + ty * 4 + i;
      if (r < M) {
#pragma unroll
        for (int jh = 0; jh < 2; ++jh) {
          ushort4 u;
          u.x = f2bf(acc[ih * 4 + i][jh * 4 + 0]);
          u.y = f2bf(acc[ih * 4 + i][jh * 4 + 1]);
          u.z = f2bf(acc[ih * 4 + i][jh * 4 + 2]);
          u.w = f2bf(acc[ih * 4 + i][jh * 4 + 3]);
          *(ushort4*)(C + (size_t)r * NCOLS + col0 + jh * 64 + tx * 4) = u;
        }
      }
    }
}

// ---------------- coord rows: xp_coord = data @ W_coord, + a_src/a_dst coord ----------------
__global__ __launch_bounds__(256) void coord_rows_kernel(
    const float* __restrict__ data, const float* __restrict__ W,
    const float* __restrict__ att_src, const float* __restrict__ att_dst,
    float* __restrict__ xp, float* __restrict__ a_src, float* __restrict__ a_dst,
    int n_nodes) {
  __shared__ float Ws[NF_IN * 12];
  int t = threadIdx.x;
#pragma unroll
  for (int i = 0; i < 6; ++i)
    *(float4*)(Ws + (i * 256 + t) * 4) = *(const float4*)(W + (i * 256 + t) * 4);
  __syncthreads();
  int warp = t >> 6, lane = t & 63;
  int n = blockIdx.x * 4 + warp;
  if (n >= n_nodes) return;
  const float* row = data + (size_t)n * NF_IN;
  float x[8];
  *(float4*)(x) = *(const float4*)(row + lane * 4);
  *(float4*)(x + 4) = *(const float4*)(row + 256 + lane * 4);
  float acc[12];
#pragma unroll
  for (int o = 0; o < 12; ++o) acc[o] = 0.f;
#pragma unroll
  for (int j = 0; j < 8; ++j) {
    int c = (j < 4) ? (lane * 4 + j) : (256 + lane * 4 + (j - 4));
    const float* wr = Ws + c * 12;
#pragma unroll
    for (int o = 0; o < 12; ++o) acc[o] += x[j] * wr[o];
  }
#pragma unroll
  for (int o = 0; o < 12; ++o) {
#pragma unroll
    for (int off = 32; off; off >>= 1) acc[o] += __shfl_xor(acc[o], off, 64);
  }
  if (lane == 0) {
    float* xr = xp + (size_t)n * 12;
#pragma unroll
    for (int o = 0; o < 12; ++o) xr[o] = acc[o];
#pragma unroll
    for (int h = 0; h < HEADS; ++h) {
      a_src[n * HEADS + h] = acc[2 * h] * att_src[2 * h] + acc[2 * h + 1] * att_src[2 * h + 1];
      a_dst[n * HEADS + h] = acc[2 * h] * att_dst[2 * h] + acc[2 * h + 1] * att_dst[2 * h + 1];
    }
  }
}

// ---------------- feat attention scores ----------------
__global__ __launch_bounds__(384) void feat_scores_kernel(
    const unsigned short* __restrict__ xp, const float* __restrict__ att_src,
    const float* __restrict__ att_dst, float* __restrict__ a_src,
    float* __restrict__ a_dst) {
  int n = blockIdx.x;
  int h = threadIdx.x >> 6;
  int lane = threadIdx.x & 63;
  ushort4 u = *(const ushort4*)(xp + (size_t)n * NCOLS + h * NF_OUT + lane * 4);
  float4 ws = *(const float4*)(att_src + h * NF_OUT + lane * 4);
  float4 wd = *(const float4*)(att_dst + h * NF_OUT + lane * 4);
  float x0 = bf2f(u.x), x1 = bf2f(u.y), x2 = bf2f(u.z), x3 = bf2f(u.w);
  float ss = x0 * ws.x + x1 * ws.y + x2 * ws.z + x3 * ws.w;
  float sd = x0 * wd.x + x1 * wd.y + x2 * wd.z + x3 * wd.w;
#pragma unroll
  for (int off = 32; off; off >>= 1) {
    ss += __shfl_xor(ss, off, 64);
    sd += __shfl_xor(sd, off, 64);
  }
  if (lane == 0) {
    a_src[n * HEADS + h] = ss;
    a_dst[n * HEADS + h] = sd;
  }
}

// ---------------- edge counting ----------------
__global__ void count_edges_kernel(const int* __restrict__ ei, int E, int Et,
                                   int* __restrict__ counts) {
  int e = blockIdx.x * blockDim.x + threadIdx.x;
  if (e >= Et) return;
  int d = (e < E) ? ei[E + e] : (e - E);
  atomicAdd(&counts[d], 1);
}

// ---------------- single-block exclusive scan -> indptr ----------------
__global__ __launch_bounds__(1024) void scan_kernel(const int* __restrict__ counts,
                                                    int* __restrict__ indptr, int n) {
  __shared__ int sm[1024];
  int t = threadIdx.x;
  if (t == 0) indptr[0] = 0;
  int base = 0;
  for (int start = 0; start < n; start += 1024) {
    int i = start + t;
    int v = (i < n) ? counts[i] : 0;
    sm[t] = v;
    __syncthreads();
    for (int off = 1; off < 1024; off <<= 1) {
      int x = (t >= off) ? sm[t - off] : 0;
      __syncthreads();
      sm[t] += x;
      __syncthreads();
    }
    int incl = sm[t];
    if (i < n) indptr[i + 1] = base + incl;
    base += sm[1023];
    __syncthreads();
  }
}

// ---------------- scatter to CSR ----------------
__global__ void scatter_kernel(const int* __restrict__ ei, int E, int Et,
                               const int* __restrict__ indptr, int* __restrict__ fill,
                               int* __restrict__ csr_src) {
  int e = blockIdx.x * blockDim.x + threadIdx.x;
  if (e >= Et) return;
  int s, d;
  if (e < E) { s = ei[e]; d = ei[E + e]; } else { s = d = e - E; }
  int pos = indptr[d] + atomicAdd(&fill[d], 1);
  csr_src[pos] = s;
}

// ---------------- per (node, head) edge softmax -> coef ----------------
__global__ void softmax_kernel(const float* __restrict__ a_src,
                               const float* __restrict__ a_dst,
                               const int* __restrict__ indptr,
                               const int* __restrict__ csr_src,
                               float* __restrict__ coef, int n_nodes) {
  int gid = blockIdx.x * blockDim.x + threadIdx.x;
  if (gid >= n_nodes * HEADS) return;
  int n = gid / HEADS, h = gid - n * HEADS;
  int e0 = indptr[n], e1 = indptr[n + 1];
  float ad = a_dst[n * HEADS + h];
  float mx = -1e30f;
  for (int p = e0; p < e1; ++p) {
    int s = csr_src[p];
    float v = a_src[s * HEADS + h] + ad;
    v = (v >= 0.f) ? v : SLOPE * v;
    mx = fmaxf(mx, v);
  }
  float sum = 0.f;
  for (int p = e0; p < e1; ++p) {
    int s = csr_src[p];
    float v = a_src[s * HEADS + h] + ad;
    v = (v >= 0.f) ? v : SLOPE * v;
    float ex = expf(v - mx);
    coef[(size_t)p * HEADS + h] = ex;
    sum += ex;
  }
  float inv = 1.f / (sum + 1e-16f);
  for (int p = e0; p < e1; ++p) coef[(size_t)p * HEADS + h] *= inv;
}

// ---------------- feat aggregation (one block per dst node) ----------------
__global__ __launch_bounds__(128) void agg_feat_kernel(
    const unsigned short* __restrict__ xp, const float* __restrict__ coef,
    const int* __restrict__ indptr, const int* __restrict__ csr_src,
    const float* __restrict__ bias, float* __restrict__ out) {
  __shared__ float accS[NF_OUT];
  int n = blockIdx.x;
  int t = threadIdx.x;
  int tdiv = t >> 6;
  int e0 = indptr[n], e1 = indptr[n + 1];
  float a0[4] = {0.f, 0.f, 0.f, 0.f};
  float a1[4] = {0.f, 0.f, 0.f, 0.f};
  float a2[4] = {0.f, 0.f, 0.f, 0.f};
  for (int p = e0; p < e1; ++p) {
    int s = csr_src[p];
    const unsigned short* xr = xp + (size_t)s * NCOLS;
    float cf0 = coef[(size_t)p * HEADS + 0 + tdiv];
    float cf1 = coef[(size_t)p * HEADS + 2 + tdiv];
    float cf2 = coef[(size_t)p * HEADS + 4 + tdiv];
    ushort4 u0 = *(const ushort4*)(xr + 0 * 512 + t * 4);
    ushort4 u1 = *(const ushort4*)(xr + 1 * 512 + t * 4);
    ushort4 u2 = *(const ushort4*)(xr + 2 * 512 + t * 4);
    a0[0] += cf0 * bf2f(u0.x); a0[1] += cf0 * bf2f(u0.y);
    a0[2] += cf0 * bf2f(u0.z); a0[3] += cf0 * bf2f(u0.w);
    a1[0] += cf1 * bf2f(u1.x); a1[1] += cf1 * bf2f(u1.y);
    a1[2] += cf1 * bf2f(u1.z); a1[3] += cf1 * bf2f(u1.w);
    a2[0] += cf2 * bf2f(u2.x); a2[1] += cf2 * bf2f(u2.y);
    a2[2] += cf2 * bf2f(u2.z); a2[3] += cf2 * bf2f(u2.w);
  }
  float p0 = a0[0] + a1[0] + a2[0];
  float p1 = a0[1] + a1[1] + a2[1];
  float p2 = a0[2] + a1[2] + a2[2];
  float p3 = a0[3] + a1[3] + a2[3];
  int c0 = (t & 63) * 4;
  if (tdiv == 0) {
    accS[c0] = p0; accS[c0 + 1] = p1; accS[c0 + 2] = p2; accS[c0 + 3] = p3;
  }
  __syncthreads();
  if (tdiv == 1) {
    accS[c0] += p0; accS[c0 + 1] += p1; accS[c0 + 2] += p2; accS[c0 + 3] += p3;
  }
  __syncthreads();
  const float selu_scale = 1.0507009873554805f;
  const float selu_alpha = 1.6732632423543772f;
  for (int c = t; c < NF_OUT; c += 128) {
    float v = accS[c] * (1.f / HEADS) + bias[c];
    v = (v > 0.f) ? selu_scale * v : selu_scale * selu_alpha * expm1f(v);
    out[(size_t)n * NF_OUT + c] = v;
  }
}

// ---------------- coord aggregation + boundary fix ----------------
__global__ void agg_coord_kernel(const float* __restrict__ xpc,
                                 const float* __restrict__ coef,
                                 const int* __restrict__ indptr,
                                 const int* __restrict__ csr_src,
                                 const float* __restrict__ bias,
                                 const float* __restrict__ data,
                                 float* __restrict__ out, int n_nodes) {
  int n = blockIdx.x * blockDim.x + threadIdx.x;
  if (n >= n_nodes) return;
  int e0 = indptr[n], e1 = indptr[n + 1];
  float acc0 = 0.f, acc1 = 0.f;
  for (int p = e0; p < e1; ++p) {
    int s = csr_src[p];
    const float* xr = xpc + (size_t)s * 12;
#pragma unroll
    for (int h = 0; h < HEADS; ++h) {
      float cf = coef[(size_t)p * HEADS + h];
      acc0 += cf * xr[2 * h];
      acc1 += cf * xr[2 * h + 1];
    }
  }
  float c0 = acc0 * (1.f / HEADS) + bias[0];
  float c1 = acc1 * (1.f / HEADS) + bias[1];
  float d0 = data[(size_t)n * NF_IN + 0];
  float d1 = data[(size_t)n * NF_IN + 1];
  if (d0 == 1.f) c0 = 1.f;
  if (d0 == 0.f) c0 = 0.f;
  if (d1 == 0.f) c1 = 0.f;
  if (d1 == 1.f) c1 = 1.f;
  out[(size_t)n * 2 + 0] = c0;
  out[(size_t)n * 2 + 1] = c1;
}

extern "C" void kernel_launch(void* const* d_in, const int* in_sizes, int n_in,
                              void* d_out, int out_size, void* d_ws, size_t ws_size,
                              hipStream_t stream) {
  const float* data = (const float*)d_in[0];
  const int* ei = (const int*)d_in[1];
  const float* W_coord = (const float*)d_in[2];
  const float* att_src_coord = (const float*)d_in[3];
  const float* att_dst_coord = (const float*)d_in[4];
  const float* b_coord = (const float*)d_in[5];
  const float* W_feat = (const float*)d_in[6];
  const float* att_src_feat = (const float*)d_in[7];
  const float* att_dst_feat = (const float*)d_in[8];
  const float* b_feat = (const float*)d_in[9];
  float* out = (float*)d_out;

  const int n = in_sizes[0] / NF_IN;   // 20000
  const int E = in_sizes[1] / 2;       // 160000
  const int Et = E + n;

  char* ws = (char*)d_ws;
  size_t o = 0;
  unsigned short* xp_feat = (unsigned short*)(ws + o); o += (size_t)n * NCOLS * 2;
  float* xp_coord = (float*)(ws + o); o += (size_t)n * 12 * 4;
  float* asf = (float*)(ws + o); o += (size_t)n * HEADS * 4;
  float* adf = (float*)(ws + o); o += (size_t)n * HEADS * 4;
  float* asc = (float*)(ws + o); o += (size_t)n * HEADS * 4;
  float* adc = (float*)(ws + o); o += (size_t)n * HEADS * 4;
  int* counts = (int*)(ws + o); o += (size_t)n * 4;
  int* fill = (int*)(ws + o); o += (size_t)n * 4;
  int* indptr = (int*)(ws + o); o += ((size_t)n + 32) * 4;
  int* csr_src = (int*)(ws + o); o += (size_t)Et * 4;
  float* coef_f = (float*)(ws + o); o += (size_t)Et * HEADS * 4;
  float* coef_c = (float*)(ws + o); o += (size_t)Et * HEADS * 4;
  if (o > ws_size) return;  // workspace insufficient — bail (will fail validation loudly)

  // 1. zero counts+fill (contiguous)
  zero_kernel<<<(2 * n + 255) / 256, 256, 0, stream>>>(counts, 2 * n);
  // 2. feat GEMM
  {
    dim3 grid(NCOLS / BN, (n + BM - 1) / BM);
    gemm_feat_kernel<<<grid, 256, 0, stream>>>(data, W_feat, xp_feat, n);
  }
  // 3. coord rows (xp_coord + coord scores)
  coord_rows_kernel<<<(n + 3) / 4, 256, 0, stream>>>(data, W_coord, att_src_coord,
                                                     att_dst_coord, xp_coord, asc, adc, n);
  // 4. feat scores
  feat_scores_kernel<<<n, 384, 0, stream>>>(xp_feat, att_src_feat, att_dst_feat, asf, adf);
  // 5. count edges
  count_edges_kernel<<<(Et + 255) / 256, 256, 0, stream>>>(ei, E, Et, counts);
  // 6. scan
  scan_kernel<<<1, 1024, 0, stream>>>(counts, indptr, n);
  // 7. scatter
  scatter_kernel<<<(Et + 255) / 256, 256, 0, stream>>>(ei, E, Et, indptr, fill, csr_src);
  // 8. softmax coefs (feat + coord)
  {
    int nb = (n * HEADS + 255) / 256;
    softmax_kernel<<<nb, 256, 0, stream>>>(asf, adf, indptr, csr_src, coef_f, n);
    softmax_kernel<<<nb, 256, 0, stream>>>(asc, adc, indptr, csr_src, coef_c, n);
  }
  // 9. feat aggregation -> out[2n ..]
  agg_feat_kernel<<<n, 128, 0, stream>>>(xp_feat, coef_f, indptr, csr_src, b_feat,
                                         out + (size_t)n * 2);
  // 10. coord aggregation + boundary -> out[0 .. 2n)
  agg_coord_kernel<<<(n + 255) / 256, 256, 0, stream>>>(xp_coord, coef_c, indptr, csr_src,
                                                        b_coord, data, out, n);
}

// Round 2
// 306.782 us; speedup vs baseline: 1.9697x; 1.9697x over previous
//
#include <hip/hip_runtime.h>
#include <hip/hip_bf16.h>
#include <math.h>

#define NF_IN 512
#define NF_OUT 256
#define HEADS 6
#define NCOLS (HEADS * NF_OUT)   // 1536
#define SLOPE 0.2f

typedef __attribute__((ext_vector_type(8))) short short8;
typedef __attribute__((ext_vector_type(4))) float f32x4;

__device__ __forceinline__ float bf2f(unsigned short u) {
  unsigned int x = ((unsigned int)u) << 16;
  return __uint_as_float(x);
}
__device__ __forceinline__ unsigned short f2bf(float f) {
  unsigned int x = __float_as_uint(f);
  unsigned int lsb = (x >> 16) & 1u;
  x += 0x7fffu + lsb;
  return (unsigned short)(x >> 16);
}

__device__ __forceinline__ void gload_lds16(const void* g, void* l) {
  __builtin_amdgcn_global_load_lds(
      (const __attribute__((address_space(1))) void*)g,
      (__attribute__((address_space(3))) void*)l, 16, 0, 0);
}

// ---------------- zero init ----------------
__global__ void zero_kernel(int* __restrict__ p, int n) {
  int i = blockIdx.x * blockDim.x + threadIdx.x;
  if (i < n) p[i] = 0;
}

// ---------------- data fp32 -> bf16 (padded rows zeroed) ----------------
__global__ void convert_data_kernel(const float* __restrict__ in,
                                    unsigned short* __restrict__ out,
                                    int total, int valid) {
  int base = (blockIdx.x * blockDim.x + threadIdx.x) * 4;
  if (base >= total) return;
  ushort4 u;
  if (base < valid) {
    float4 v = *(const float4*)(in + base);
    u.x = f2bf(v.x); u.y = f2bf(v.y); u.z = f2bf(v.z); u.w = f2bf(v.w);
  } else {
    u.x = 0; u.y = 0; u.z = 0; u.w = 0;
  }
  *(ushort4*)(out + base) = u;
}

// ---------------- W_feat [512][1536] fp32 -> Wt [1536][512] bf16 ----------------
__global__ __launch_bounds__(256) void transpose_w_kernel(
    const float* __restrict__ W, unsigned short* __restrict__ Wt) {
  __shared__ float tileS[32][33];
  int c0 = blockIdx.x * 32;   // col of W
  int k0 = blockIdx.y * 32;   // row of W
  int t = threadIdx.x;
  int tr = t >> 5;  // 0..7
  int tc = t & 31;
#pragma unroll
  for (int j = 0; j < 4; ++j)
    tileS[tr * 4 + j][tc] = W[(size_t)(k0 + tr * 4 + j) * NCOLS + c0 + tc];
  __syncthreads();
#pragma unroll
  for (int j = 0; j < 4; ++j)
    Wt[(size_t)(c0 + tr * 4 + j) * NF_IN + k0 + tc] = f2bf(tileS[tc][tr * 4 + j]);
}

// ---------------- bf16 MFMA GEMM: xp_feat = data @ W_feat ----------------
// A: [Mpad][512] bf16 row-major, Bt: [1536][512] bf16 (W^T), C: [M][1536] bf16
#define GBM 128
#define GBN 128
#define GBK 32
__global__ __launch_bounds__(256) void gemm_mfma_kernel(
    const unsigned short* __restrict__ A, const unsigned short* __restrict__ Bt,
    unsigned short* __restrict__ C, int M) {
  __shared__ __align__(16) unsigned short sA[GBM * GBK];  // [128][32]
  __shared__ __align__(16) unsigned short sB[GBN * GBK];  // [128 cols][32 k]
  const int tid = threadIdx.x;
  const int wid = tid >> 6;
  const int lane = tid & 63;
  const int row0 = blockIdx.y * GBM;
  const int col0 = blockIdx.x * GBN;
  const int wr = (wid >> 1) * 64;
  const int wc = (wid & 1) * 64;

  f32x4 acc[4][4] = {};

  // staging: issue i covers rows i*64 + tid/4, 16B each (kseg = tid%4)
  const int arow = tid >> 2;
  const int kseg = tid & 3;
  const unsigned short* gA = A + (size_t)(row0 + arow) * NF_IN + kseg * 8;
  const unsigned short* gB = Bt + (size_t)(col0 + arow) * NF_IN + kseg * 8;
  unsigned short* lA = sA + wid * 512;   // wave-uniform LDS base (1024 B/wave)
  unsigned short* lB = sB + wid * 512;

  const int fr = lane & 15;
  const int fk = (lane >> 4) * 8;

  for (int k0 = 0; k0 < NF_IN; k0 += GBK) {
    gload_lds16(gA + k0, lA);
    gload_lds16(gA + 64 * NF_IN + k0, lA + 2048);
    gload_lds16(gB + k0, lB);
    gload_lds16(gB + 64 * NF_IN + k0, lB + 2048);
    __syncthreads();
    short8 af[4], bfr[4];
#pragma unroll
    for (int m = 0; m < 4; ++m)
      af[m] = *(const short8*)(sA + (wr + m * 16 + fr) * GBK + fk);
#pragma unroll
    for (int nn = 0; nn < 4; ++nn)
      bfr[nn] = *(const short8*)(sB + (wc + nn * 16 + fr) * GBK + fk);
#pragma unroll
    for (int m = 0; m < 4; ++m)
#pragma unroll
      for (int nn = 0; nn < 4; ++nn)
        acc[m][nn] = __builtin_amdgcn_mfma_f32_16x16x32_bf16(af[m], bfr[nn],
                                                             acc[m][nn], 0, 0, 0);
    __syncthreads();
  }

  const int dcol = lane & 15;
  const int g4 = (lane >> 4) * 4;
#pragma unroll
  for (int m = 0; m < 4; ++m) {
#pragma unroll
    for (int i = 0; i < 4; ++i) {
      int r = row0 + wr + m * 16 + g4 + i;
      if (r < M) {
#pragma unroll
        for (int nn = 0; nn < 4; ++nn)
          C[(size_t)r * NCOLS + col0 + wc + nn * 16 + dcol] = f2bf(acc[m][nn][i]);
      }
    }
  }
}

// ---------------- coord rows: xp_coord = data @ W_coord, + a_src/a_dst coord ----------------
__global__ __launch_bounds__(256) void coord_rows_kernel(
    const float* __restrict__ data, const float* __restrict__ W,
    const float* __restrict__ att_src, const float* __restrict__ att_dst,
    float* __restrict__ xp, float* __restrict__ a_src, float* __restrict__ a_dst,
    int n_nodes) {
  __shared__ float Ws[NF_IN * 12];
  int t = threadIdx.x;
#pragma unroll
  for (int i = 0; i < 6; ++i)
    *(float4*)(Ws + (i * 256 + t) * 4) = *(const float4*)(W + (i * 256 + t) * 4);
  __syncthreads();
  int warp = t >> 6, lane = t & 63;
  int n = blockIdx.x * 4 + warp;
  if (n >= n_nodes) return;
  const float* row = data + (size_t)n * NF_IN;
  float x[8];
  *(float4*)(x) = *(const float4*)(row + lane * 4);
  *(float4*)(x + 4) = *(const float4*)(row + 256 + lane * 4);
  float acc[12];
#pragma unroll
  for (int o = 0; o < 12; ++o) acc[o] = 0.f;
#pragma unroll
  for (int j = 0; j < 8; ++j) {
    int c = (j < 4) ? (lane * 4 + j) : (256 + lane * 4 + (j - 4));
    const float* wr = Ws + c * 12;
#pragma unroll
    for (int o = 0; o < 12; ++o) acc[o] += x[j] * wr[o];
  }
#pragma unroll
  for (int o = 0; o < 12; ++o) {
#pragma unroll
    for (int off = 32; off; off >>= 1) acc[o] += __shfl_xor(acc[o], off, 64);
  }
  if (lane == 0) {
    float* xr = xp + (size_t)n * 12;
#pragma unroll
    for (int o = 0; o < 12; ++o) xr[o] = acc[o];
#pragma unroll
    for (int h = 0; h < HEADS; ++h) {
      a_src[n * HEADS + h] = acc[2 * h] * att_src[2 * h] + acc[2 * h + 1] * att_src[2 * h + 1];
      a_dst[n * HEADS + h] = acc[2 * h] * att_dst[2 * h] + acc[2 * h + 1] * att_dst[2 * h + 1];
    }
  }
}

// ---------------- feat attention scores ----------------
__global__ __launch_bounds__(384) void feat_scores_kernel(
    const unsigned short* __restrict__ xp, const float* __restrict__ att_src,
    const float* __restrict__ att_dst, float* __restrict__ a_src,
    float* __restrict__ a_dst) {
  int n = blockIdx.x;
  int h = threadIdx.x >> 6;
  int lane = threadIdx.x & 63;
  ushort4 u = *(const ushort4*)(xp + (size_t)n * NCOLS + h * NF_OUT + lane * 4);
  float4 ws = *(const float4*)(att_src + h * NF_OUT + lane * 4);
  float4 wd = *(const float4*)(att_dst + h * NF_OUT + lane * 4);
  float x0 = bf2f(u.x), x1 = bf2f(u.y), x2 = bf2f(u.z), x3 = bf2f(u.w);
  float ss = x0 * ws.x + x1 * ws.y + x2 * ws.z + x3 * ws.w;
  float sd = x0 * wd.x + x1 * wd.y + x2 * wd.z + x3 * wd.w;
#pragma unroll
  for (int off = 32; off; off >>= 1) {
    ss += __shfl_xor(ss, off, 64);
    sd += __shfl_xor(sd, off, 64);
  }
  if (lane == 0) {
    a_src[n * HEADS + h] = ss;
    a_dst[n * HEADS + h] = sd;
  }
}

// ---------------- edge counting ----------------
__global__ void count_edges_kernel(const int* __restrict__ ei, int E, int Et,
                                   int* __restrict__ counts) {
  int e = blockIdx.x * blockDim.x + threadIdx.x;
  if (e >= Et) return;
  int d = (e < E) ? ei[E + e] : (e - E);
  atomicAdd(&counts[d], 1);
}

// ---------------- single-block exclusive scan -> indptr ----------------
__global__ __launch_bounds__(1024) void scan_kernel(const int* __restrict__ counts,
                                                    int* __restrict__ indptr, int n) {
  __shared__ int sm[1024];
  int t = threadIdx.x;
  if (t == 0) indptr[0] = 0;
  int base = 0;
  for (int start = 0; start < n; start += 1024) {
    int i = start + t;
    int v = (i < n) ? counts[i] : 0;
    sm[t] = v;
    __syncthreads();
    for (int off = 1; off < 1024; off <<= 1) {
      int x = (t >= off) ? sm[t - off] : 0;
      __syncthreads();
      sm[t] += x;
      __syncthreads();
    }
    int incl = sm[t];
    if (i < n) indptr[i + 1] = base + incl;
    base += sm[1023];
    __syncthreads();
  }
}

// ---------------- scatter to CSR ----------------
__global__ void scatter_kernel(const int* __restrict__ ei, int E, int Et,
                               const int* __restrict__ indptr, int* __restrict__ fill,
                               int* __restrict__ csr_src) {
  int e = blockIdx.x * blockDim.x + threadIdx.x;
  if (e >= Et) return;
  int s, d;
  if (e < E) { s = ei[e]; d = ei[E + e]; } else { s = d = e - E; }
  int pos = indptr[d] + atomicAdd(&fill[d], 1);
  csr_src[pos] = s;
}

// ---------------- per (node, head) edge softmax -> coef ----------------
__global__ void softmax_kernel(const float* __restrict__ a_src,
                               const float* __restrict__ a_dst,
                               const int* __restrict__ indptr,
                               const int* __restrict__ csr_src,
                               float* __restrict__ coef, int n_nodes) {
  int gid = blockIdx.x * blockDim.x + threadIdx.x;
  if (gid >= n_nodes * HEADS) return;
  int n = gid / HEADS, h = gid - n * HEADS;
  int e0 = indptr[n], e1 = indptr[n + 1];
  float ad = a_dst[n * HEADS + h];
  float mx = -1e30f;
  for (int p = e0; p < e1; ++p) {
    int s = csr_src[p];
    float v = a_src[s * HEADS + h] + ad;
    v = (v >= 0.f) ? v : SLOPE * v;
    mx = fmaxf(mx, v);
  }
  float sum = 0.f;
  for (int p = e0; p < e1; ++p) {
    int s = csr_src[p];
    float v = a_src[s * HEADS + h] + ad;
    v = (v >= 0.f) ? v : SLOPE * v;
    float ex = expf(v - mx);
    coef[(size_t)p * HEADS + h] = ex;
    sum += ex;
  }
  float inv = 1.f / (sum + 1e-16f);
  for (int p = e0; p < e1; ++p) coef[(size_t)p * HEADS + h] *= inv;
}

// ---------------- feat aggregation (one block per dst node) ----------------
__global__ __launch_bounds__(128) void agg_feat_kernel(
    const unsigned short* __restrict__ xp, const float* __restrict__ coef,
    const int* __restrict__ indptr, const int* __restrict__ csr_src,
    const float* __restrict__ bias, float* __restrict__ out) {
  __shared__ float accS[NF_OUT];
  int n = blockIdx.x;
  int t = threadIdx.x;
  int tdiv = t >> 6;
  int e0 = indptr[n], e1 = indptr[n + 1];
  float a0[4] = {0.f, 0.f, 0.f, 0.f};
  float a1[4] = {0.f, 0.f, 0.f, 0.f};
  float a2[4] = {0.f, 0.f, 0.f, 0.f};
  for (int p = e0; p < e1; ++p) {
    int s = csr_src[p];
    const unsigned short* xr = xp + (size_t)s * NCOLS;
    float cf0 = coef[(size_t)p * HEADS + 0 + tdiv];
    float cf1 = coef[(size_t)p * HEADS + 2 + tdiv];
    float cf2 = coef[(size_t)p * HEADS + 4 + tdiv];
    ushort4 u0 = *(const ushort4*)(xr + 0 * 512 + t * 4);
    ushort4 u1 = *(const ushort4*)(xr + 1 * 512 + t * 4);
    ushort4 u2 = *(const ushort4*)(xr + 2 * 512 + t * 4);
    a0[0] += cf0 * bf2f(u0.x); a0[1] += cf0 * bf2f(u0.y);
    a0[2] += cf0 * bf2f(u0.z); a0[3] += cf0 * bf2f(u0.w);
    a1[0] += cf1 * bf2f(u1.x); a1[1] += cf1 * bf2f(u1.y);
    a1[2] += cf1 * bf2f(u1.z); a1[3] += cf1 * bf2f(u1.w);
    a2[0] += cf2 * bf2f(u2.x); a2[1] += cf2 * bf2f(u2.y);
    a2[2] += cf2 * bf2f(u2.z); a2[3] += cf2 * bf2f(u2.w);
  }
  float p0 = a0[0] + a1[0] + a2[0];
  float p1 = a0[1] + a1[1] + a2[1];
  float p2 = a0[2] + a1[2] + a2[2];
  float p3 = a0[3] + a1[3] + a2[3];
  int c0 = (t & 63) * 4;
  if (tdiv == 0) {
    accS[c0] = p0; accS[c0 + 1] = p1; accS[c0 + 2] = p2; accS[c0 + 3] = p3;
  }
  __syncthreads();
  if (tdiv == 1) {
    accS[c0] += p0; accS[c0 + 1] += p1; accS[c0 + 2] += p2; accS[c0 + 3] += p3;
  }
  __syncthreads();
  const float selu_scale = 1.0507009873554805f;
  const float selu_alpha = 1.6732632423543772f;
  for (int c = t; c < NF_OUT; c += 128) {
    float v = accS[c] * (1.f / HEADS) + bias[c];
    v = (v > 0.f) ? selu_scale * v : selu_scale * selu_alpha * expm1f(v);
    out[(size_t)n * NF_OUT + c] = v;
  }
}

// ---------------- coord aggregation + boundary fix ----------------
__global__ void agg_coord_kernel(const float* __restrict__ xpc,
                                 const float* __restrict__ coef,
                                 const int* __restrict__ indptr,
                                 const int* __restrict__ csr_src,
                                 const float* __restrict__ bias,
                                 const float* __restrict__ data,
                                 float* __restrict__ out, int n_nodes) {
  int n = blockIdx.x * blockDim.x + threadIdx.x;
  if (n >= n_nodes) return;
  int e0 = indptr[n], e1 = indptr[n + 1];
  float acc0 = 0.f, acc1 = 0.f;
  for (int p = e0; p < e1; ++p) {
    int s = csr_src[p];
    const float* xr = xpc + (size_t)s * 12;
#pragma unroll
    for (int h = 0; h < HEADS; ++h) {
      float cf = coef[(size_t)p * HEADS + h];
      acc0 += cf * xr[2 * h];
      acc1 += cf * xr[2 * h + 1];
    }
  }
  float c0 = acc0 * (1.f / HEADS) + bias[0];
  float c1 = acc1 * (1.f / HEADS) + bias[1];
  float d0 = data[(size_t)n * NF_IN + 0];
  float d1 = data[(size_t)n * NF_IN + 1];
  if (d0 == 1.f) c0 = 1.f;
  if (d0 == 0.f) c0 = 0.f;
  if (d1 == 0.f) c1 = 0.f;
  if (d1 == 1.f) c1 = 1.f;
  out[(size_t)n * 2 + 0] = c0;
  out[(size_t)n * 2 + 1] = c1;
}

extern "C" void kernel_launch(void* const* d_in, const int* in_sizes, int n_in,
                              void* d_out, int out_size, void* d_ws, size_t ws_size,
                              hipStream_t stream) {
  const float* data = (const float*)d_in[0];
  const int* ei = (const int*)d_in[1];
  const float* W_coord = (const float*)d_in[2];
  const float* att_src_coord = (const float*)d_in[3];
  const float* att_dst_coord = (const float*)d_in[4];
  const float* b_coord = (const float*)d_in[5];
  const float* W_feat = (const float*)d_in[6];
  const float* att_src_feat = (const float*)d_in[7];
  const float* att_dst_feat = (const float*)d_in[8];
  const float* b_feat = (const float*)d_in[9];
  float* out = (float*)d_out;

  const int n = in_sizes[0] / NF_IN;   // 20000
  const int E = in_sizes[1] / 2;       // 160000
  const int Et = E + n;
  const int Mpad = ((n + GBM - 1) / GBM) * GBM;  // 20096

  char* ws = (char*)d_ws;
  size_t o = 0;
  unsigned short* xp_feat = (unsigned short*)(ws + o); o += (size_t)n * NCOLS * 2;
  unsigned short* data_bf = (unsigned short*)(ws + o); o += (size_t)Mpad * NF_IN * 2;
  unsigned short* wt_bf = (unsigned short*)(ws + o); o += (size_t)NCOLS * NF_IN * 2;
  float* xp_coord = (float*)(ws + o); o += (size_t)n * 12 * 4;
  float* asf = (float*)(ws + o); o += (size_t)n * HEADS * 4;
  float* adf = (float*)(ws + o); o += (size_t)n * HEADS * 4;
  float* asc = (float*)(ws + o); o += (size_t)n * HEADS * 4;
  float* adc = (float*)(ws + o); o += (size_t)n * HEADS * 4;
  int* counts = (int*)(ws + o); o += (size_t)n * 4;
  int* fill = (int*)(ws + o); o += (size_t)n * 4;
  int* indptr = (int*)(ws + o); o += ((size_t)n + 32) * 4;
  int* csr_src = (int*)(ws + o); o += (size_t)Et * 4;
  float* coef_f = (float*)(ws + o); o += (size_t)Et * HEADS * 4;
  float* coef_c = (float*)(ws + o); o += (size_t)Et * HEADS * 4;
  if (o > ws_size) return;  // workspace insufficient — fail loudly

  // 1. zero counts+fill (contiguous)
  zero_kernel<<<(2 * n + 255) / 256, 256, 0, stream>>>(counts, 2 * n);
  // 2a. convert data -> bf16 (padded)
  {
    int total = Mpad * NF_IN, valid = n * NF_IN;
    convert_data_kernel<<<(total / 4 + 255) / 256, 256, 0, stream>>>(data, data_bf,
                                                                     total, valid);
  }
  // 2b. transpose W_feat -> bf16
  {
    dim3 grid(NCOLS / 32, NF_IN / 32);
    transpose_w_kernel<<<grid, 256, 0, stream>>>(W_feat, wt_bf);
  }
  // 2c. feat GEMM (bf16 MFMA)
  {
    dim3 grid(NCOLS / GBN, Mpad / GBM);
    gemm_mfma_kernel<<<grid, 256, 0, stream>>>(data_bf, wt_bf, xp_feat, n);
  }
  // 3. coord rows (xp_coord + coord scores)
  coord_rows_kernel<<<(n + 3) / 4, 256, 0, stream>>>(data, W_coord, att_src_coord,
                                                     att_dst_coord, xp_coord, asc, adc, n);
  // 4. feat scores
  feat_scores_kernel<<<n, 384, 0, stream>>>(xp_feat, att_src_feat, att_dst_feat, asf, adf);
  // 5. count edges
  count_edges_kernel<<<(Et + 255) / 256, 256, 0, stream>>>(ei, E, Et, counts);
  // 6. scan
  scan_kernel<<<1, 1024, 0, stream>>>(counts, indptr, n);
  // 7. scatter
  scatter_kernel<<<(Et + 255) / 256, 256, 0, stream>>>(ei, E, Et, indptr, fill, csr_src);
  // 8. softmax coefs (feat + coord)
  {
    int nb = (n * HEADS + 255) / 256;
    softmax_kernel<<<nb, 256, 0, stream>>>(asf, adf, indptr, csr_src, coef_f, n);
    softmax_kernel<<<nb, 256, 0, stream>>>(asc, adc, indptr, csr_src, coef_c, n);
  }
  // 9. feat aggregation -> out[2n ..]
  agg_feat_kernel<<<n, 128, 0, stream>>>(xp_feat, coef_f, indptr, csr_src, b_feat,
                                         out + (size_t)n * 2);
  // 10. coord aggregation + boundary -> out[0 .. 2n)
  agg_coord_kernel<<<(n + 255) / 256, 256, 0, stream>>>(xp_coord, coef_c, indptr, csr_src,
                                                        b_coord, data, out, n);
}

// Round 3
// 295.281 us; speedup vs baseline: 2.0464x; 1.0389x over previous
//
#include <hip/hip_runtime.h>
#include <hip/hip_bf16.h>
#include <math.h>

#define NF_IN 512
#define NF_OUT 256
#define HEADS 6
#define NCOLS (HEADS * NF_OUT)   // 1536
#define SLOPE 0.2f

typedef __attribute__((ext_vector_type(8))) short short8;
typedef __attribute__((ext_vector_type(4))) float f32x4;

__device__ __forceinline__ float bf2f(unsigned short u) {
  unsigned int x = ((unsigned int)u) << 16;
  return __uint_as_float(x);
}
__device__ __forceinline__ unsigned short f2bf(float f) {
  unsigned int x = __float_as_uint(f);
  unsigned int lsb = (x >> 16) & 1u;
  x += 0x7fffu + lsb;
  return (unsigned short)(x >> 16);
}

__device__ __forceinline__ void gload_lds16(const void* g, void* l) {
  __builtin_amdgcn_global_load_lds(
      (const __attribute__((address_space(1))) void*)g,
      (__attribute__((address_space(3))) void*)l, 16, 0, 0);
}

// ---------------- zero init ----------------
__global__ void zero_kernel(int* __restrict__ p, int n) {
  int i = blockIdx.x * blockDim.x + threadIdx.x;
  if (i < n) p[i] = 0;
}

// ---------------- fused: data->bf16 convert + coord matvec + coord scores ----------------
__global__ __launch_bounds__(256) void prep_data_kernel(
    const float* __restrict__ data, const float* __restrict__ W,
    const float* __restrict__ att_src, const float* __restrict__ att_dst,
    unsigned short* __restrict__ data_bf, float* __restrict__ xp,
    float* __restrict__ a_src, float* __restrict__ a_dst, int n_nodes, int m_pad) {
  __shared__ float Ws[NF_IN * 12];
  int t = threadIdx.x;
#pragma unroll
  for (int i = 0; i < 6; ++i)
    *(float4*)(Ws + (i * 256 + t) * 4) = *(const float4*)(W + (i * 256 + t) * 4);
  __syncthreads();
  int warp = t >> 6, lane = t & 63;
  int n = blockIdx.x * 4 + warp;
  if (n >= m_pad) return;
  if (n >= n_nodes) {  // pad rows: zero bf16
    ushort4 z = {0, 0, 0, 0};
    *(ushort4*)(data_bf + (size_t)n * NF_IN + lane * 4) = z;
    *(ushort4*)(data_bf + (size_t)n * NF_IN + 256 + lane * 4) = z;
    return;
  }
  const float* row = data + (size_t)n * NF_IN;
  float x[8];
  *(float4*)(x) = *(const float4*)(row + lane * 4);
  *(float4*)(x + 4) = *(const float4*)(row + 256 + lane * 4);
  // bf16 row out
  ushort4 u0, u1;
  u0.x = f2bf(x[0]); u0.y = f2bf(x[1]); u0.z = f2bf(x[2]); u0.w = f2bf(x[3]);
  u1.x = f2bf(x[4]); u1.y = f2bf(x[5]); u1.z = f2bf(x[6]); u1.w = f2bf(x[7]);
  *(ushort4*)(data_bf + (size_t)n * NF_IN + lane * 4) = u0;
  *(ushort4*)(data_bf + (size_t)n * NF_IN + 256 + lane * 4) = u1;
  // coord matvec
  float acc[12];
#pragma unroll
  for (int o = 0; o < 12; ++o) acc[o] = 0.f;
#pragma unroll
  for (int j = 0; j < 8; ++j) {
    int c = (j < 4) ? (lane * 4 + j) : (256 + lane * 4 + (j - 4));
    const float* wr = Ws + c * 12;
#pragma unroll
    for (int o = 0; o < 12; ++o) acc[o] += x[j] * wr[o];
  }
#pragma unroll
  for (int o = 0; o < 12; ++o) {
#pragma unroll
    for (int off = 32; off; off >>= 1) acc[o] += __shfl_xor(acc[o], off, 64);
  }
  if (lane == 0) {
    float* xr = xp + (size_t)n * 12;
#pragma unroll
    for (int o = 0; o < 12; ++o) xr[o] = acc[o];
#pragma unroll
    for (int h = 0; h < HEADS; ++h) {
      a_src[n * HEADS + h] = acc[2 * h] * att_src[2 * h] + acc[2 * h + 1] * att_src[2 * h + 1];
      a_dst[n * HEADS + h] = acc[2 * h] * att_dst[2 * h] + acc[2 * h + 1] * att_dst[2 * h + 1];
    }
  }
}

// ---------------- W_feat [512][1536] fp32 -> Wt [1536][512] bf16 ----------------
__global__ __launch_bounds__(256) void transpose_w_kernel(
    const float* __restrict__ W, unsigned short* __restrict__ Wt) {
  __shared__ float tileS[32][33];
  int c0 = blockIdx.x * 32;
  int k0 = blockIdx.y * 32;
  int t = threadIdx.x;
  int tr = t >> 5;
  int tc = t & 31;
#pragma unroll
  for (int j = 0; j < 4; ++j)
    tileS[tr * 4 + j][tc] = W[(size_t)(k0 + tr * 4 + j) * NCOLS + c0 + tc];
  __syncthreads();
#pragma unroll
  for (int j = 0; j < 4; ++j)
    Wt[(size_t)(c0 + tr * 4 + j) * NF_IN + k0 + tc] = f2bf(tileS[tc][tr * 4 + j]);
}

// ---------------- bf16 MFMA GEMM ----------------
#define GBM 128
#define GBN 128
#define GBK 32
__global__ __launch_bounds__(256) void gemm_mfma_kernel(
    const unsigned short* __restrict__ A, const unsigned short* __restrict__ Bt,
    unsigned short* __restrict__ C, int M) {
  __shared__ __align__(16) unsigned short sA[GBM * GBK];
  __shared__ __align__(16) unsigned short sB[GBN * GBK];
  const int tid = threadIdx.x;
  const int wid = tid >> 6;
  const int lane = tid & 63;
  const int row0 = blockIdx.y * GBM;
  const int col0 = blockIdx.x * GBN;
  const int wr = (wid >> 1) * 64;
  const int wc = (wid & 1) * 64;

  f32x4 acc[4][4] = {};

  const int arow = tid >> 2;
  const int kseg = tid & 3;
  const unsigned short* gA = A + (size_t)(row0 + arow) * NF_IN + kseg * 8;
  const unsigned short* gB = Bt + (size_t)(col0 + arow) * NF_IN + kseg * 8;
  unsigned short* lA = sA + wid * 512;
  unsigned short* lB = sB + wid * 512;

  const int fr = lane & 15;
  const int fk = (lane >> 4) * 8;

  for (int k0 = 0; k0 < NF_IN; k0 += GBK) {
    gload_lds16(gA + k0, lA);
    gload_lds16(gA + 64 * NF_IN + k0, lA + 2048);
    gload_lds16(gB + k0, lB);
    gload_lds16(gB + 64 * NF_IN + k0, lB + 2048);
    __syncthreads();
    short8 af[4], bfr[4];
#pragma unroll
    for (int m = 0; m < 4; ++m)
      af[m] = *(const short8*)(sA + (wr + m * 16 + fr) * GBK + fk);
#pragma unroll
    for (int nn = 0; nn < 4; ++nn)
      bfr[nn] = *(const short8*)(sB + (wc + nn * 16 + fr) * GBK + fk);
#pragma unroll
    for (int m = 0; m < 4; ++m)
#pragma unroll
      for (int nn = 0; nn < 4; ++nn)
        acc[m][nn] = __builtin_amdgcn_mfma_f32_16x16x32_bf16(af[m], bfr[nn],
                                                             acc[m][nn], 0, 0, 0);
    __syncthreads();
  }

  const int dcol = lane & 15;
  const int g4 = (lane >> 4) * 4;
#pragma unroll
  for (int m = 0; m < 4; ++m) {
#pragma unroll
    for (int i = 0; i < 4; ++i) {
      int r = row0 + wr + m * 16 + g4 + i;
      if (r < M) {
#pragma unroll
        for (int nn = 0; nn < 4; ++nn)
          C[(size_t)r * NCOLS + col0 + wc + nn * 16 + dcol] = f2bf(acc[m][nn][i]);
      }
    }
  }
}

// ---------------- feat attention scores ----------------
__global__ __launch_bounds__(384) void feat_scores_kernel(
    const unsigned short* __restrict__ xp, const float* __restrict__ att_src,
    const float* __restrict__ att_dst, float* __restrict__ a_src,
    float* __restrict__ a_dst) {
  int n = blockIdx.x;
  int h = threadIdx.x >> 6;
  int lane = threadIdx.x & 63;
  ushort4 u = *(const ushort4*)(xp + (size_t)n * NCOLS + h * NF_OUT + lane * 4);
  float4 ws = *(const float4*)(att_src + h * NF_OUT + lane * 4);
  float4 wd = *(const float4*)(att_dst + h * NF_OUT + lane * 4);
  float x0 = bf2f(u.x), x1 = bf2f(u.y), x2 = bf2f(u.z), x3 = bf2f(u.w);
  float ss = x0 * ws.x + x1 * ws.y + x2 * ws.z + x3 * ws.w;
  float sd = x0 * wd.x + x1 * wd.y + x2 * wd.z + x3 * wd.w;
#pragma unroll
  for (int off = 32; off; off >>= 1) {
    ss += __shfl_xor(ss, off, 64);
    sd += __shfl_xor(sd, off, 64);
  }
  if (lane == 0) {
    a_src[n * HEADS + h] = ss;
    a_dst[n * HEADS + h] = sd;
  }
}

// ---------------- edge counting ----------------
__global__ void count_edges_kernel(const int* __restrict__ ei, int E, int Et,
                                   int* __restrict__ counts) {
  int e = blockIdx.x * blockDim.x + threadIdx.x;
  if (e >= Et) return;
  int d = (e < E) ? ei[E + e] : (e - E);
  atomicAdd(&counts[d], 1);
}

// ---------------- fast single-block exclusive scan -> indptr ----------------
__global__ __launch_bounds__(1024) void scan_kernel(const int* __restrict__ counts,
                                                    int* __restrict__ indptr, int n) {
  __shared__ int wsum[16];
  const int CH = (n + 1023) >> 10;
  int t = threadIdx.x, lane = t & 63, w = t >> 6;
  int base = t * CH;
  int run = 0;
  for (int i = 0; i < CH; ++i) {
    int idx = base + i;
    run += (idx < n) ? counts[idx] : 0;
  }
  int tot = run;
#pragma unroll
  for (int off = 1; off < 64; off <<= 1) {
    int x = __shfl_up(tot, off, 64);
    if (lane >= off) tot += x;
  }
  if (lane == 63) wsum[w] = tot;
  __syncthreads();
  if (t == 0) {
    int s = 0;
#pragma unroll
    for (int i = 0; i < 16; ++i) { int x = wsum[i]; wsum[i] = s; s += x; }
  }
  __syncthreads();
  int run2 = wsum[w] + (tot - run);  // exclusive prefix for this thread's chunk
  if (t == 0) indptr[0] = 0;
  for (int i = 0; i < CH; ++i) {
    int idx = base + i;
    if (idx < n) {
      run2 += counts[idx];
      indptr[idx + 1] = run2;
    }
  }
}

// ---------------- scatter to CSR ----------------
__global__ void scatter_kernel(const int* __restrict__ ei, int E, int Et,
                               const int* __restrict__ indptr, int* __restrict__ fill,
                               int* __restrict__ csr_src) {
  int e = blockIdx.x * blockDim.x + threadIdx.x;
  if (e >= Et) return;
  int s, d;
  if (e < E) { s = ei[e]; d = ei[E + e]; } else { s = d = e - E; }
  int pos = indptr[d] + atomicAdd(&fill[d], 1);
  csr_src[pos] = s;
}

// ---------------- per (node, head) edge softmax -> coef ----------------
// Pass 1 gathers a_src once, caches leaky value in coef; passes 2/3 are sequential.
__global__ void softmax_kernel(const float* __restrict__ a_src,
                               const float* __restrict__ a_dst,
                               const int* __restrict__ indptr,
                               const int* __restrict__ csr_src,
                               float* __restrict__ coef, int n_nodes) {
  int gid = blockIdx.x * blockDim.x + threadIdx.x;
  if (gid >= n_nodes * HEADS) return;
  int n = gid / HEADS, h = gid - n * HEADS;
  int e0 = indptr[n], e1 = indptr[n + 1];
  float ad = a_dst[n * HEADS + h];
  float mx = -1e30f;
  for (int p = e0; p < e1; ++p) {
    int s = csr_src[p];
    float v = a_src[s * HEADS + h] + ad;
    v = (v >= 0.f) ? v : SLOPE * v;
    coef[(size_t)p * HEADS + h] = v;
    mx = fmaxf(mx, v);
  }
  float sum = 0.f;
  for (int p = e0; p < e1; ++p) {
    float ex = __expf(coef[(size_t)p * HEADS + h] - mx);
    coef[(size_t)p * HEADS + h] = ex;
    sum += ex;
  }
  float inv = 1.f / (sum + 1e-16f);
  for (int p = e0; p < e1; ++p) coef[(size_t)p * HEADS + h] *= inv;
}

// ---------------- feat aggregation: 6 waves/node, 4-edge ILP, LDS-staged csr ----------------
#define AGG_CSR_CAP 768
__global__ __launch_bounds__(384) void agg_feat_kernel(
    const unsigned short* __restrict__ xp, const float* __restrict__ coef,
    const int* __restrict__ indptr, const int* __restrict__ csr_src,
    const float* __restrict__ bias, float* __restrict__ out) {
  __shared__ float accS[HEADS][NF_OUT];
  __shared__ int smCsr[AGG_CSR_CAP];
  int n = blockIdx.x;
  int t = threadIdx.x;        // 0..383
  int w = t >> 6;             // head 0..5
  int lane = t & 63;
  int e0 = indptr[n], e1 = indptr[n + 1];
  int deg = e1 - e0;
  bool useLds = (deg <= AGG_CSR_CAP);
  if (useLds) {
    for (int i = t; i < deg; i += 384) smCsr[i] = csr_src[e0 + i];
  }
  __syncthreads();
  const unsigned short* xph = xp + w * NF_OUT + lane * 4;
  float a0[4] = {0, 0, 0, 0}, a1[4] = {0, 0, 0, 0};
  float a2[4] = {0, 0, 0, 0}, a3[4] = {0, 0, 0, 0};
  int p = e0;
  for (; p + 4 <= e1; p += 4) {
    int i0 = p - e0;
    int s0 = useLds ? smCsr[i0] : csr_src[p];
    int s1 = useLds ? smCsr[i0 + 1] : csr_src[p + 1];
    int s2 = useLds ? smCsr[i0 + 2] : csr_src[p + 2];
    int s3 = useLds ? smCsr[i0 + 3] : csr_src[p + 3];
    float c0 = coef[(size_t)p * HEADS + w];
    float c1 = coef[(size_t)(p + 1) * HEADS + w];
    float c2 = coef[(size_t)(p + 2) * HEADS + w];
    float c3 = coef[(size_t)(p + 3) * HEADS + w];
    ushort4 u0 = *(const ushort4*)(xph + (size_t)s0 * NCOLS);
    ushort4 u1 = *(const ushort4*)(xph + (size_t)s1 * NCOLS);
    ushort4 u2 = *(const ushort4*)(xph + (size_t)s2 * NCOLS);
    ushort4 u3 = *(const ushort4*)(xph + (size_t)s3 * NCOLS);
    a0[0] += c0 * bf2f(u0.x); a0[1] += c0 * bf2f(u0.y);
    a0[2] += c0 * bf2f(u0.z); a0[3] += c0 * bf2f(u0.w);
    a1[0] += c1 * bf2f(u1.x); a1[1] += c1 * bf2f(u1.y);
    a1[2] += c1 * bf2f(u1.z); a1[3] += c1 * bf2f(u1.w);
    a2[0] += c2 * bf2f(u2.x); a2[1] += c2 * bf2f(u2.y);
    a2[2] += c2 * bf2f(u2.z); a2[3] += c2 * bf2f(u2.w);
    a3[0] += c3 * bf2f(u3.x); a3[1] += c3 * bf2f(u3.y);
    a3[2] += c3 * bf2f(u3.z); a3[3] += c3 * bf2f(u3.w);
  }
  for (; p < e1; ++p) {
    int s0 = useLds ? smCsr[p - e0] : csr_src[p];
    float c0 = coef[(size_t)p * HEADS + w];
    ushort4 u0 = *(const ushort4*)(xph + (size_t)s0 * NCOLS);
    a0[0] += c0 * bf2f(u0.x); a0[1] += c0 * bf2f(u0.y);
    a0[2] += c0 * bf2f(u0.z); a0[3] += c0 * bf2f(u0.w);
  }
  float4 r;
  r.x = a0[0] + a1[0] + a2[0] + a3[0];
  r.y = a0[1] + a1[1] + a2[1] + a3[1];
  r.z = a0[2] + a1[2] + a2[2] + a3[2];
  r.w = a0[3] + a1[3] + a2[3] + a3[3];
  *(float4*)(&accS[w][lane * 4]) = r;
  __syncthreads();
  if (t < NF_OUT) {
    float s = accS[0][t] + accS[1][t] + accS[2][t] + accS[3][t] + accS[4][t] + accS[5][t];
    const float selu_scale = 1.0507009873554805f;
    const float selu_alpha = 1.6732632423543772f;
    float v = s * (1.f / HEADS) + bias[t];
    v = (v > 0.f) ? selu_scale * v : selu_scale * selu_alpha * expm1f(v);
    out[(size_t)n * NF_OUT + t] = v;
  }
}

// ---------------- coord aggregation + boundary fix (2-edge ILP) ----------------
__global__ void agg_coord_kernel(const float* __restrict__ xpc,
                                 const float* __restrict__ coef,
                                 const int* __restrict__ indptr,
                                 const int* __restrict__ csr_src,
                                 const float* __restrict__ bias,
                                 const float* __restrict__ data,
                                 float* __restrict__ out, int n_nodes) {
  int n = blockIdx.x * blockDim.x + threadIdx.x;
  if (n >= n_nodes) return;
  int e0 = indptr[n], e1 = indptr[n + 1];
  float b00 = 0.f, b01 = 0.f, b10 = 0.f, b11 = 0.f;
  int p = e0;
  for (; p + 2 <= e1; p += 2) {
    int s0 = csr_src[p], s1 = csr_src[p + 1];
    const float* x0 = xpc + (size_t)s0 * 12;
    const float* x1 = xpc + (size_t)s1 * 12;
#pragma unroll
    for (int h = 0; h < HEADS; ++h) {
      float c0 = coef[(size_t)p * HEADS + h];
      float c1 = coef[(size_t)(p + 1) * HEADS + h];
      b00 += c0 * x0[2 * h]; b01 += c0 * x0[2 * h + 1];
      b10 += c1 * x1[2 * h]; b11 += c1 * x1[2 * h + 1];
    }
  }
  if (p < e1) {
    int s0 = csr_src[p];
    const float* x0 = xpc + (size_t)s0 * 12;
#pragma unroll
    for (int h = 0; h < HEADS; ++h) {
      float c0 = coef[(size_t)p * HEADS + h];
      b00 += c0 * x0[2 * h]; b01 += c0 * x0[2 * h + 1];
    }
  }
  float c0 = (b00 + b10) * (1.f / HEADS) + bias[0];
  float c1 = (b01 + b11) * (1.f / HEADS) + bias[1];
  float d0 = data[(size_t)n * NF_IN + 0];
  float d1 = data[(size_t)n * NF_IN + 1];
  if (d0 == 1.f) c0 = 1.f;
  if (d0 == 0.f) c0 = 0.f;
  if (d1 == 0.f) c1 = 0.f;
  if (d1 == 1.f) c1 = 1.f;
  out[(size_t)n * 2 + 0] = c0;
  out[(size_t)n * 2 + 1] = c1;
}

extern "C" void kernel_launch(void* const* d_in, const int* in_sizes, int n_in,
                              void* d_out, int out_size, void* d_ws, size_t ws_size,
                              hipStream_t stream) {
  const float* data = (const float*)d_in[0];
  const int* ei = (const int*)d_in[1];
  const float* W_coord = (const float*)d_in[2];
  const float* att_src_coord = (const float*)d_in[3];
  const float* att_dst_coord = (const float*)d_in[4];
  const float* b_coord = (const float*)d_in[5];
  const float* W_feat = (const float*)d_in[6];
  const float* att_src_feat = (const float*)d_in[7];
  const float* att_dst_feat = (const float*)d_in[8];
  const float* b_feat = (const float*)d_in[9];
  float* out = (float*)d_out;

  const int n = in_sizes[0] / NF_IN;   // 20000
  const int E = in_sizes[1] / 2;       // 160000
  const int Et = E + n;
  const int Mpad = ((n + GBM - 1) / GBM) * GBM;  // 20096

  char* ws = (char*)d_ws;
  size_t o = 0;
  unsigned short* xp_feat = (unsigned short*)(ws + o); o += (size_t)n * NCOLS * 2;
  unsigned short* data_bf = (unsigned short*)(ws + o); o += (size_t)Mpad * NF_IN * 2;
  unsigned short* wt_bf = (unsigned short*)(ws + o); o += (size_t)NCOLS * NF_IN * 2;
  float* xp_coord = (float*)(ws + o); o += (size_t)n * 12 * 4;
  float* asf = (float*)(ws + o); o += (size_t)n * HEADS * 4;
  float* adf = (float*)(ws + o); o += (size_t)n * HEADS * 4;
  float* asc = (float*)(ws + o); o += (size_t)n * HEADS * 4;
  float* adc = (float*)(ws + o); o += (size_t)n * HEADS * 4;
  int* counts = (int*)(ws + o); o += (size_t)n * 4;
  int* fill = (int*)(ws + o); o += (size_t)n * 4;
  int* indptr = (int*)(ws + o); o += ((size_t)n + 32) * 4;
  int* csr_src = (int*)(ws + o); o += (size_t)Et * 4;
  float* coef_f = (float*)(ws + o); o += (size_t)Et * HEADS * 4;
  float* coef_c = (float*)(ws + o); o += (size_t)Et * HEADS * 4;
  if (o > ws_size) return;  // workspace insufficient — fail loudly

  // 1. zero counts+fill
  zero_kernel<<<(2 * n + 255) / 256, 256, 0, stream>>>(counts, 2 * n);
  // 2. fused convert + coord rows
  prep_data_kernel<<<(Mpad + 3) / 4, 256, 0, stream>>>(data, W_coord, att_src_coord,
                                                       att_dst_coord, data_bf, xp_coord,
                                                       asc, adc, n, Mpad);
  // 3. transpose W_feat
  {
    dim3 grid(NCOLS / 32, NF_IN / 32);
    transpose_w_kernel<<<grid, 256, 0, stream>>>(W_feat, wt_bf);
  }
  // 4. feat GEMM (bf16 MFMA)
  {
    dim3 grid(NCOLS / GBN, Mpad / GBM);
    gemm_mfma_kernel<<<grid, 256, 0, stream>>>(data_bf, wt_bf, xp_feat, n);
  }
  // 5. feat scores
  feat_scores_kernel<<<n, 384, 0, stream>>>(xp_feat, att_src_feat, att_dst_feat, asf, adf);
  // 6. count edges
  count_edges_kernel<<<(Et + 255) / 256, 256, 0, stream>>>(ei, E, Et, counts);
  // 7. scan
  scan_kernel<<<1, 1024, 0, stream>>>(counts, indptr, n);
  // 8. scatter
  scatter_kernel<<<(Et + 255) / 256, 256, 0, stream>>>(ei, E, Et, indptr, fill, csr_src);
  // 9. softmax coefs (feat + coord)
  {
    int nb = (n * HEADS + 255) / 256;
    softmax_kernel<<<nb, 256, 0, stream>>>(asf, adf, indptr, csr_src, coef_f, n);
    softmax_kernel<<<nb, 256, 0, stream>>>(asc, adc, indptr, csr_src, coef_c, n);
  }
  // 10. feat aggregation -> out[2n ..]
  agg_feat_kernel<<<n, 384, 0, stream>>>(xp_feat, coef_f, indptr, csr_src, b_feat,
                                         out + (size_t)n * 2);
  // 11. coord aggregation + boundary -> out[0 .. 2n)
  agg_coord_kernel<<<(n + 255) / 256, 256, 0, stream>>>(xp_coord, coef_c, indptr, csr_src,
                                                        b_coord, data, out, n);
}

// Round 4
// 274.840 us; speedup vs baseline: 2.1986x; 1.0744x over previous
//
#include <hip/hip_runtime.h>
#include <hip/hip_bf16.h>
#include <math.h>

#define NF_IN 512
#define NF_OUT 256
#define HEADS 6
#define NCOLS (HEADS * NF_OUT)   // 1536
#define SLOPE 0.2f

typedef __attribute__((ext_vector_type(8))) short short8;
typedef __attribute__((ext_vector_type(4))) float f32x4;

__device__ __forceinline__ float bf2f(unsigned short u) {
  unsigned int x = ((unsigned int)u) << 16;
  return __uint_as_float(x);
}
__device__ __forceinline__ unsigned short f2bf(float f) {
  unsigned int x = __float_as_uint(f);
  unsigned int lsb = (x >> 16) & 1u;
  x += 0x7fffu + lsb;
  return (unsigned short)(x >> 16);
}

__device__ __forceinline__ void gload_lds16(const void* g, void* l) {
  __builtin_amdgcn_global_load_lds(
      (const __attribute__((address_space(1))) void*)g,
      (__attribute__((address_space(3))) void*)l, 16, 0, 0);
}

// ---------------- zero init ----------------
__global__ void zero_kernel(int* __restrict__ p, int n) {
  int i = blockIdx.x * blockDim.x + threadIdx.x;
  if (i < n) p[i] = 0;
}

// ---------------- fused: data->bf16 convert + coord matvec + coord scores ----------------
__global__ __launch_bounds__(256) void prep_data_kernel(
    const float* __restrict__ data, const float* __restrict__ W,
    const float* __restrict__ att_src, const float* __restrict__ att_dst,
    unsigned short* __restrict__ data_bf, float* __restrict__ xp,
    float* __restrict__ a_src, float* __restrict__ a_dst, int n_nodes, int m_pad) {
  __shared__ float Ws[NF_IN * 12];
  int t = threadIdx.x;
#pragma unroll
  for (int i = 0; i < 6; ++i)
    *(float4*)(Ws + (i * 256 + t) * 4) = *(const float4*)(W + (i * 256 + t) * 4);
  __syncthreads();
  int warp = t >> 6, lane = t & 63;
  int n = blockIdx.x * 4 + warp;
  if (n >= m_pad) return;
  if (n >= n_nodes) {  // pad rows: zero bf16
    ushort4 z = {0, 0, 0, 0};
    *(ushort4*)(data_bf + (size_t)n * NF_IN + lane * 4) = z;
    *(ushort4*)(data_bf + (size_t)n * NF_IN + 256 + lane * 4) = z;
    return;
  }
  const float* row = data + (size_t)n * NF_IN;
  float x[8];
  *(float4*)(x) = *(const float4*)(row + lane * 4);
  *(float4*)(x + 4) = *(const float4*)(row + 256 + lane * 4);
  ushort4 u0, u1;
  u0.x = f2bf(x[0]); u0.y = f2bf(x[1]); u0.z = f2bf(x[2]); u0.w = f2bf(x[3]);
  u1.x = f2bf(x[4]); u1.y = f2bf(x[5]); u1.z = f2bf(x[6]); u1.w = f2bf(x[7]);
  *(ushort4*)(data_bf + (size_t)n * NF_IN + lane * 4) = u0;
  *(ushort4*)(data_bf + (size_t)n * NF_IN + 256 + lane * 4) = u1;
  float acc[12];
#pragma unroll
  for (int o = 0; o < 12; ++o) acc[o] = 0.f;
#pragma unroll
  for (int j = 0; j < 8; ++j) {
    int c = (j < 4) ? (lane * 4 + j) : (256 + lane * 4 + (j - 4));
    const float* wr = Ws + c * 12;
#pragma unroll
    for (int o = 0; o < 12; ++o) acc[o] += x[j] * wr[o];
  }
#pragma unroll
  for (int o = 0; o < 12; ++o) {
#pragma unroll
    for (int off = 32; off; off >>= 1) acc[o] += __shfl_xor(acc[o], off, 64);
  }
  if (lane == 0) {
    float* xr = xp + (size_t)n * 12;
#pragma unroll
    for (int o = 0; o < 12; ++o) xr[o] = acc[o];
#pragma unroll
    for (int h = 0; h < HEADS; ++h) {
      a_src[n * HEADS + h] = acc[2 * h] * att_src[2 * h] + acc[2 * h + 1] * att_src[2 * h + 1];
      a_dst[n * HEADS + h] = acc[2 * h] * att_dst[2 * h] + acc[2 * h + 1] * att_dst[2 * h + 1];
    }
  }
}

// ---------------- W_feat [512][1536] fp32 -> Wt [1536][512] bf16 ----------------
__global__ __launch_bounds__(256) void transpose_w_kernel(
    const float* __restrict__ W, unsigned short* __restrict__ Wt) {
  __shared__ float tileS[32][33];
  int c0 = blockIdx.x * 32;
  int k0 = blockIdx.y * 32;
  int t = threadIdx.x;
  int tr = t >> 5;
  int tc = t & 31;
#pragma unroll
  for (int j = 0; j < 4; ++j)
    tileS[tr * 4 + j][tc] = W[(size_t)(k0 + tr * 4 + j) * NCOLS + c0 + tc];
  __syncthreads();
#pragma unroll
  for (int j = 0; j < 4; ++j)
    Wt[(size_t)(c0 + tr * 4 + j) * NF_IN + k0 + tc] = f2bf(tileS[tc][tr * 4 + j]);
}

// ---------------- bf16 MFMA GEMM ----------------
#define GBM 128
#define GBN 128
#define GBK 32
__global__ __launch_bounds__(256) void gemm_mfma_kernel(
    const unsigned short* __restrict__ A, const unsigned short* __restrict__ Bt,
    unsigned short* __restrict__ C, int M) {
  __shared__ __align__(16) unsigned short sA[GBM * GBK];
  __shared__ __align__(16) unsigned short sB[GBN * GBK];
  const int tid = threadIdx.x;
  const int wid = tid >> 6;
  const int lane = tid & 63;
  const int row0 = blockIdx.y * GBM;
  const int col0 = blockIdx.x * GBN;
  const int wr = (wid >> 1) * 64;
  const int wc = (wid & 1) * 64;

  f32x4 acc[4][4] = {};

  const int arow = tid >> 2;
  const int kseg = tid & 3;
  const unsigned short* gA = A + (size_t)(row0 + arow) * NF_IN + kseg * 8;
  const unsigned short* gB = Bt + (size_t)(col0 + arow) * NF_IN + kseg * 8;
  unsigned short* lA = sA + wid * 512;
  unsigned short* lB = sB + wid * 512;

  const int fr = lane & 15;
  const int fk = (lane >> 4) * 8;

  for (int k0 = 0; k0 < NF_IN; k0 += GBK) {
    gload_lds16(gA + k0, lA);
    gload_lds16(gA + 64 * NF_IN + k0, lA + 2048);
    gload_lds16(gB + k0, lB);
    gload_lds16(gB + 64 * NF_IN + k0, lB + 2048);
    __syncthreads();
    short8 af[4], bfr[4];
#pragma unroll
    for (int m = 0; m < 4; ++m)
      af[m] = *(const short8*)(sA + (wr + m * 16 + fr) * GBK + fk);
#pragma unroll
    for (int nn = 0; nn < 4; ++nn)
      bfr[nn] = *(const short8*)(sB + (wc + nn * 16 + fr) * GBK + fk);
#pragma unroll
    for (int m = 0; m < 4; ++m)
#pragma unroll
      for (int nn = 0; nn < 4; ++nn)
        acc[m][nn] = __builtin_amdgcn_mfma_f32_16x16x32_bf16(af[m], bfr[nn],
                                                             acc[m][nn], 0, 0, 0);
    __syncthreads();
  }

  const int dcol = lane & 15;
  const int g4 = (lane >> 4) * 4;
#pragma unroll
  for (int m = 0; m < 4; ++m) {
#pragma unroll
    for (int i = 0; i < 4; ++i) {
      int r = row0 + wr + m * 16 + g4 + i;
      if (r < M) {
#pragma unroll
        for (int nn = 0; nn < 4; ++nn)
          C[(size_t)r * NCOLS + col0 + wc + nn * 16 + dcol] = f2bf(acc[m][nn][i]);
      }
    }
  }
}

// ---------------- feat attention scores ----------------
__global__ __launch_bounds__(384) void feat_scores_kernel(
    const unsigned short* __restrict__ xp, const float* __restrict__ att_src,
    const float* __restrict__ att_dst, float* __restrict__ a_src,
    float* __restrict__ a_dst) {
  int n = blockIdx.x;
  int h = threadIdx.x >> 6;
  int lane = threadIdx.x & 63;
  ushort4 u = *(const ushort4*)(xp + (size_t)n * NCOLS + h * NF_OUT + lane * 4);
  float4 ws = *(const float4*)(att_src + h * NF_OUT + lane * 4);
  float4 wd = *(const float4*)(att_dst + h * NF_OUT + lane * 4);
  float x0 = bf2f(u.x), x1 = bf2f(u.y), x2 = bf2f(u.z), x3 = bf2f(u.w);
  float ss = x0 * ws.x + x1 * ws.y + x2 * ws.z + x3 * ws.w;
  float sd = x0 * wd.x + x1 * wd.y + x2 * wd.z + x3 * wd.w;
#pragma unroll
  for (int off = 32; off; off >>= 1) {
    ss += __shfl_xor(ss, off, 64);
    sd += __shfl_xor(sd, off, 64);
  }
  if (lane == 0) {
    a_src[n * HEADS + h] = ss;
    a_dst[n * HEADS + h] = sd;
  }
}

// ---------------- edge counting ----------------
__global__ void count_edges_kernel(const int* __restrict__ ei, int E, int Et,
                                   int* __restrict__ counts) {
  int e = blockIdx.x * blockDim.x + threadIdx.x;
  if (e >= Et) return;
  int d = (e < E) ? ei[E + e] : (e - E);
  atomicAdd(&counts[d], 1);
}

// ---------------- fast single-block exclusive scan -> indptr ----------------
__global__ __launch_bounds__(1024) void scan_kernel(const int* __restrict__ counts,
                                                    int* __restrict__ indptr, int n) {
  __shared__ int wsum[16];
  const int CH = (n + 1023) >> 10;
  int t = threadIdx.x, lane = t & 63, w = t >> 6;
  int base = t * CH;
  int run = 0;
  for (int i = 0; i < CH; ++i) {
    int idx = base + i;
    run += (idx < n) ? counts[idx] : 0;
  }
  int tot = run;
#pragma unroll
  for (int off = 1; off < 64; off <<= 1) {
    int x = __shfl_up(tot, off, 64);
    if (lane >= off) tot += x;
  }
  if (lane == 63) wsum[w] = tot;
  __syncthreads();
  if (t == 0) {
    int s = 0;
#pragma unroll
    for (int i = 0; i < 16; ++i) { int x = wsum[i]; wsum[i] = s; s += x; }
  }
  __syncthreads();
  int run2 = wsum[w] + (tot - run);
  if (t == 0) indptr[0] = 0;
  for (int i = 0; i < CH; ++i) {
    int idx = base + i;
    if (idx < n) {
      run2 += counts[idx];
      indptr[idx + 1] = run2;
    }
  }
}

// ---------------- scatter to CSR ----------------
__global__ void scatter_kernel(const int* __restrict__ ei, int E, int Et,
                               const int* __restrict__ indptr, int* __restrict__ fill,
                               int* __restrict__ csr_src) {
  int e = blockIdx.x * blockDim.x + threadIdx.x;
  if (e >= Et) return;
  int s, d;
  if (e < E) { s = ei[e]; d = ei[E + e]; } else { s = d = e - E; }
  int pos = indptr[d] + atomicAdd(&fill[d], 1);
  csr_src[pos] = s;
}

// ---------------- fused per (node, head) edge softmax: feat + coord in one walk ----------------
__global__ void softmax2_kernel(const float* __restrict__ asf, const float* __restrict__ adf,
                                const float* __restrict__ asc, const float* __restrict__ adc,
                                const int* __restrict__ indptr,
                                const int* __restrict__ csr_src,
                                float* __restrict__ coef_f, float* __restrict__ coef_c,
                                int n_nodes) {
  int gid = blockIdx.x * blockDim.x + threadIdx.x;
  if (gid >= n_nodes * HEADS) return;
  int n = gid / HEADS, h = gid - n * HEADS;
  int e0 = indptr[n], e1 = indptr[n + 1];
  float adF = adf[n * HEADS + h];
  float adC = adc[n * HEADS + h];
  float mxF = -1e30f, mxC = -1e30f;
  for (int p = e0; p < e1; ++p) {
    int s = csr_src[p];
    float vF = asf[s * HEADS + h] + adF;
    float vC = asc[s * HEADS + h] + adC;
    vF = (vF >= 0.f) ? vF : SLOPE * vF;
    vC = (vC >= 0.f) ? vC : SLOPE * vC;
    coef_f[(size_t)p * HEADS + h] = vF;
    coef_c[(size_t)p * HEADS + h] = vC;
    mxF = fmaxf(mxF, vF);
    mxC = fmaxf(mxC, vC);
  }
  float sF = 0.f, sC = 0.f;
  for (int p = e0; p < e1; ++p) {
    float eF = __expf(coef_f[(size_t)p * HEADS + h] - mxF);
    float eC = __expf(coef_c[(size_t)p * HEADS + h] - mxC);
    coef_f[(size_t)p * HEADS + h] = eF;
    coef_c[(size_t)p * HEADS + h] = eC;
    sF += eF;
    sC += eC;
  }
  float iF = 1.f / (sF + 1e-16f);
  float iC = 1.f / (sC + 1e-16f);
  for (int p = e0; p < e1; ++p) {
    coef_f[(size_t)p * HEADS + h] *= iF;
    coef_c[(size_t)p * HEADS + h] *= iC;
  }
}

// ---------------- feat aggregation: wave-per-node, whole row per wave ----------------
// Lane l, chunk j covers elems j*512 + l*8 .. +8 of the 1536-row.
// head(j,l) = 2j + (l>>5); col = (l&31)*8 + i. Lane l and l^32 hold the
// complementary head triples for the same cols -> one shfl_xor(32) finishes
// the head sum; lanes <32 store cols (l*8..l*8+8).
__global__ __launch_bounds__(256) void agg_feat_kernel(
    const unsigned short* __restrict__ xp, const float* __restrict__ coef,
    const int* __restrict__ indptr, const int* __restrict__ csr_src,
    const float* __restrict__ bias, float* __restrict__ out, int n_nodes) {
  int wid = threadIdx.x >> 6;
  int lane = threadIdx.x & 63;
  int n = blockIdx.x * 4 + wid;
  if (n >= n_nodes) return;
  int e0 = indptr[n], e1 = indptr[n + 1];
  int hhalf = lane >> 5;
  const unsigned short* xpl = xp + lane * 8;
  float acc[3][8];
#pragma unroll
  for (int j = 0; j < 3; ++j)
#pragma unroll
    for (int i = 0; i < 8; ++i) acc[j][i] = 0.f;

  int p = e0;
  for (; p + 4 <= e1; p += 4) {
    int s0 = csr_src[p], s1 = csr_src[p + 1], s2 = csr_src[p + 2], s3 = csr_src[p + 3];
    ushort4 u[4][3];
    const unsigned short* r0 = xpl + (size_t)s0 * NCOLS;
    const unsigned short* r1 = xpl + (size_t)s1 * NCOLS;
    const unsigned short* r2 = xpl + (size_t)s2 * NCOLS;
    const unsigned short* r3 = xpl + (size_t)s3 * NCOLS;
#pragma unroll
    for (int j = 0; j < 3; ++j) {
      u[0][j] = *(const ushort4*)(r0 + j * 512);
      u[1][j] = *(const ushort4*)(r1 + j * 512);
      u[2][j] = *(const ushort4*)(r2 + j * 512);
      u[3][j] = *(const ushort4*)(r3 + j * 512);
    }
    float cf[4][3];
#pragma unroll
    for (int e = 0; e < 4; ++e)
#pragma unroll
      for (int j = 0; j < 3; ++j)
        cf[e][j] = coef[(size_t)(p + e) * HEADS + 2 * j + hhalf];
#pragma unroll
    for (int e = 0; e < 4; ++e)
#pragma unroll
      for (int j = 0; j < 3; ++j) {
        float c = cf[e][j];
        acc[j][0] += c * bf2f(u[e][j].x);
        acc[j][1] += c * bf2f(u[e][j].y);
        acc[j][2] += c * bf2f(u[e][j].z);
        acc[j][3] += c * bf2f(u[e][j].w);
        // upper half of the 8 elems
        ushort4 uu = *(const ushort4*)((const unsigned short*)&u[e][j] + 0);
        (void)uu;
      }
    // second ushort4 of each 8-elem chunk handled below via separate loads
    // (see u2 array)
    ushort4 v[4][3];
#pragma unroll
    for (int j = 0; j < 3; ++j) {
      v[0][j] = *(const ushort4*)(r0 + j * 512 + 4);
      v[1][j] = *(const ushort4*)(r1 + j * 512 + 4);
      v[2][j] = *(const ushort4*)(r2 + j * 512 + 4);
      v[3][j] = *(const ushort4*)(r3 + j * 512 + 4);
    }
#pragma unroll
    for (int e = 0; e < 4; ++e)
#pragma unroll
      for (int j = 0; j < 3; ++j) {
        float c = cf[e][j];
        acc[j][4] += c * bf2f(v[e][j].x);
        acc[j][5] += c * bf2f(v[e][j].y);
        acc[j][6] += c * bf2f(v[e][j].z);
        acc[j][7] += c * bf2f(v[e][j].w);
      }
  }
  for (; p < e1; ++p) {
    int s0 = csr_src[p];
    const unsigned short* r0 = xpl + (size_t)s0 * NCOLS;
#pragma unroll
    for (int j = 0; j < 3; ++j) {
      float c = coef[(size_t)p * HEADS + 2 * j + hhalf];
      ushort4 a = *(const ushort4*)(r0 + j * 512);
      ushort4 b = *(const ushort4*)(r0 + j * 512 + 4);
      acc[j][0] += c * bf2f(a.x); acc[j][1] += c * bf2f(a.y);
      acc[j][2] += c * bf2f(a.z); acc[j][3] += c * bf2f(a.w);
      acc[j][4] += c * bf2f(b.x); acc[j][5] += c * bf2f(b.y);
      acc[j][6] += c * bf2f(b.z); acc[j][7] += c * bf2f(b.w);
    }
  }
  float r[8];
#pragma unroll
  for (int i = 0; i < 8; ++i) {
    r[i] = acc[0][i] + acc[1][i] + acc[2][i];
    r[i] += __shfl_xor(r[i], 32, 64);
  }
  if (lane < 32) {
    const float selu_scale = 1.0507009873554805f;
    const float selu_alpha = 1.6732632423543772f;
    int c0 = lane * 8;
    float4 o0, o1;
    float* rp = r;
#pragma unroll
    for (int i = 0; i < 8; ++i) {
      float v = rp[i] * (1.f / HEADS) + bias[c0 + i];
      rp[i] = (v > 0.f) ? selu_scale * v : selu_scale * selu_alpha * expm1f(v);
    }
    o0.x = rp[0]; o0.y = rp[1]; o0.z = rp[2]; o0.w = rp[3];
    o1.x = rp[4]; o1.y = rp[5]; o1.z = rp[6]; o1.w = rp[7];
    *(float4*)(out + (size_t)n * NF_OUT + c0) = o0;
    *(float4*)(out + (size_t)n * NF_OUT + c0 + 4) = o1;
  }
}

// ---------------- coord aggregation + boundary fix (2-edge ILP) ----------------
__global__ void agg_coord_kernel(const float* __restrict__ xpc,
                                 const float* __restrict__ coef,
                                 const int* __restrict__ indptr,
                                 const int* __restrict__ csr_src,
                                 const float* __restrict__ bias,
                                 const float* __restrict__ data,
                                 float* __restrict__ out, int n_nodes) {
  int n = blockIdx.x * blockDim.x + threadIdx.x;
  if (n >= n_nodes) return;
  int e0 = indptr[n], e1 = indptr[n + 1];
  float b00 = 0.f, b01 = 0.f, b10 = 0.f, b11 = 0.f;
  int p = e0;
  for (; p + 2 <= e1; p += 2) {
    int s0 = csr_src[p], s1 = csr_src[p + 1];
    const float* x0 = xpc + (size_t)s0 * 12;
    const float* x1 = xpc + (size_t)s1 * 12;
#pragma unroll
    for (int h = 0; h < HEADS; ++h) {
      float c0 = coef[(size_t)p * HEADS + h];
      float c1 = coef[(size_t)(p + 1) * HEADS + h];
      b00 += c0 * x0[2 * h]; b01 += c0 * x0[2 * h + 1];
      b10 += c1 * x1[2 * h]; b11 += c1 * x1[2 * h + 1];
    }
  }
  if (p < e1) {
    int s0 = csr_src[p];
    const float* x0 = xpc + (size_t)s0 * 12;
#pragma unroll
    for (int h = 0; h < HEADS; ++h) {
      float c0 = coef[(size_t)p * HEADS + h];
      b00 += c0 * x0[2 * h]; b01 += c0 * x0[2 * h + 1];
    }
  }
  float c0 = (b00 + b10) * (1.f / HEADS) + bias[0];
  float c1 = (b01 + b11) * (1.f / HEADS) + bias[1];
  float d0 = data[(size_t)n * NF_IN + 0];
  float d1 = data[(size_t)n * NF_IN + 1];
  if (d0 == 1.f) c0 = 1.f;
  if (d0 == 0.f) c0 = 0.f;
  if (d1 == 0.f) c1 = 0.f;
  if (d1 == 1.f) c1 = 1.f;
  out[(size_t)n * 2 + 0] = c0;
  out[(size_t)n * 2 + 1] = c1;
}

extern "C" void kernel_launch(void* const* d_in, const int* in_sizes, int n_in,
                              void* d_out, int out_size, void* d_ws, size_t ws_size,
                              hipStream_t stream) {
  const float* data = (const float*)d_in[0];
  const int* ei = (const int*)d_in[1];
  const float* W_coord = (const float*)d_in[2];
  const float* att_src_coord = (const float*)d_in[3];
  const float* att_dst_coord = (const float*)d_in[4];
  const float* b_coord = (const float*)d_in[5];
  const float* W_feat = (const float*)d_in[6];
  const float* att_src_feat = (const float*)d_in[7];
  const float* att_dst_feat = (const float*)d_in[8];
  const float* b_feat = (const float*)d_in[9];
  float* out = (float*)d_out;

  const int n = in_sizes[0] / NF_IN;   // 20000
  const int E = in_sizes[1] / 2;       // 160000
  const int Et = E + n;
  const int Mpad = ((n + GBM - 1) / GBM) * GBM;  // 20096

  char* ws = (char*)d_ws;
  size_t o = 0;
  unsigned short* xp_feat = (unsigned short*)(ws + o); o += (size_t)n * NCOLS * 2;
  unsigned short* data_bf = (unsigned short*)(ws + o); o += (size_t)Mpad * NF_IN * 2;
  unsigned short* wt_bf = (unsigned short*)(ws + o); o += (size_t)NCOLS * NF_IN * 2;
  float* xp_coord = (float*)(ws + o); o += (size_t)n * 12 * 4;
  float* asf = (float*)(ws + o); o += (size_t)n * HEADS * 4;
  float* adf = (float*)(ws + o); o += (size_t)n * HEADS * 4;
  float* asc = (float*)(ws + o); o += (size_t)n * HEADS * 4;
  float* adc = (float*)(ws + o); o += (size_t)n * HEADS * 4;
  int* counts = (int*)(ws + o); o += (size_t)n * 4;
  int* fill = (int*)(ws + o); o += (size_t)n * 4;
  int* indptr = (int*)(ws + o); o += ((size_t)n + 32) * 4;
  int* csr_src = (int*)(ws + o); o += (size_t)Et * 4;
  float* coef_f = (float*)(ws + o); o += (size_t)Et * HEADS * 4;
  float* coef_c = (float*)(ws + o); o += (size_t)Et * HEADS * 4;
  if (o > ws_size) return;  // workspace insufficient — fail loudly

  // 1. zero counts+fill
  zero_kernel<<<(2 * n + 255) / 256, 256, 0, stream>>>(counts, 2 * n);
  // 2. fused convert + coord rows
  prep_data_kernel<<<(Mpad + 3) / 4, 256, 0, stream>>>(data, W_coord, att_src_coord,
                                                       att_dst_coord, data_bf, xp_coord,
                                                       asc, adc, n, Mpad);
  // 3. transpose W_feat
  {
    dim3 grid(NCOLS / 32, NF_IN / 32);
    transpose_w_kernel<<<grid, 256, 0, stream>>>(W_feat, wt_bf);
  }
  // 4. feat GEMM (bf16 MFMA)
  {
    dim3 grid(NCOLS / GBN, Mpad / GBM);
    gemm_mfma_kernel<<<grid, 256, 0, stream>>>(data_bf, wt_bf, xp_feat, n);
  }
  // 5. feat scores
  feat_scores_kernel<<<n, 384, 0, stream>>>(xp_feat, att_src_feat, att_dst_feat, asf, adf);
  // 6. count edges
  count_edges_kernel<<<(Et + 255) / 256, 256, 0, stream>>>(ei, E, Et, counts);
  // 7. scan
  scan_kernel<<<1, 1024, 0, stream>>>(counts, indptr, n);
  // 8. scatter
  scatter_kernel<<<(Et + 255) / 256, 256, 0, stream>>>(ei, E, Et, indptr, fill, csr_src);
  // 9. fused softmax coefs (feat + coord in one walk)
  {
    int nb = (n * HEADS + 255) / 256;
    softmax2_kernel<<<nb, 256, 0, stream>>>(asf, adf, asc, adc, indptr, csr_src,
                                            coef_f, coef_c, n);
  }
  // 10. feat aggregation -> out[2n ..]
  agg_feat_kernel<<<(n + 3) / 4, 256, 0, stream>>>(xp_feat, coef_f, indptr, csr_src,
                                                   b_feat, out + (size_t)n * 2, n);
  // 11. coord aggregation + boundary -> out[0 .. 2n)
  agg_coord_kernel<<<(n + 255) / 256, 256, 0, stream>>>(xp_coord, coef_c, indptr, csr_src,
                                                        b_coord, data, out, n);
}